// Round 6
// baseline (231.956 us; speedup 1.0000x reference)
//
#include <hip/hip_runtime.h>
#include <hip/hip_bf16.h>
#include <cstdint>
#include <cstddef>

#define DMODEL 1024
#define NHEADS 16
#define DK 64
#define SEQ 2048
#define BATCH 2
#define NT (SEQ / 32)

typedef short bf16x8 __attribute__((ext_vector_type(8)));
typedef float f32x4 __attribute__((ext_vector_type(4)));
typedef float f32x16 __attribute__((ext_vector_type(16)));
typedef unsigned int u32x2 __attribute__((ext_vector_type(2)));
typedef unsigned int u32x4 __attribute__((ext_vector_type(4)));

typedef const __attribute__((address_space(1))) void* gas_ptr;
typedef __attribute__((address_space(3))) void* las_ptr;

__device__ __forceinline__ void gld_lds16(const void* g, void* l) {
    __builtin_amdgcn_global_load_lds((gas_ptr)g, (las_ptr)l, 16, 0, 0);
}

__device__ __forceinline__ ushort f2bf_u(float f) {
    uint32_t x = __float_as_uint(f);
    x += 0x7fff + ((x >> 16) & 1);   // RNE
    return (ushort)(x >> 16);
}

// ---------------- fused cast fp32 -> bf16 (7 arrays, 1 launch) ----------------
__global__ __launch_bounds__(256) void cast_all(
        const float* __restrict__ q, const float* __restrict__ k,
        const float* __restrict__ v, const float* __restrict__ Wq,
        const float* __restrict__ Wk, const float* __restrict__ Wv,
        const float* __restrict__ Wo,
        ushort* __restrict__ qb, ushort* __restrict__ kb, ushort* __restrict__ vb,
        ushort* __restrict__ Wqb, ushort* __restrict__ Wkb,
        ushort* __restrict__ Wvb, ushort* __restrict__ Wob) {
    int bid = blockIdx.x;
    const float* src; ushort* dst; int base;
    if      (bid <  4096) { src = q;  dst = qb;  base = bid; }
    else if (bid <  8192) { src = k;  dst = kb;  base = bid - 4096; }
    else if (bid < 12288) { src = v;  dst = vb;  base = bid - 8192; }
    else if (bid < 13312) { src = Wq; dst = Wqb; base = bid - 12288; }
    else if (bid < 14336) { src = Wk; dst = Wkb; base = bid - 13312; }
    else if (bid < 15360) { src = Wv; dst = Wvb; base = bid - 14336; }
    else                  { src = Wo; dst = Wob; base = bid - 15360; }
    int i = base * 1024 + threadIdx.x * 4;
    float4 f = *reinterpret_cast<const float4*>(src + i);
    ushort4 o;
    o.x = f2bf_u(f.x); o.y = f2bf_u(f.y); o.z = f2bf_u(f.z); o.w = f2bf_u(f.w);
    *reinterpret_cast<ushort4*>(dst + i) = o;
}

// ---------------- mask -> additive bias (fp32) ----------------
__global__ __launch_bounds__(256) void mask2bias(
        const int* __restrict__ m, float* __restrict__ mb) {
    int i = (blockIdx.x * 256 + threadIdx.x) * 4;
    int4 mk = *reinterpret_cast<const int4*>(m + i);
    float4 o;
    o.x = mk.x ? 0.f : -1e9f;
    o.y = mk.y ? 0.f : -1e9f;
    o.z = mk.z ? 0.f : -1e9f;
    o.w = mk.w ? 0.f : -1e9f;
    *reinterpret_cast<float4*>(mb + i) = o;
}

// ---------------- GEMM: C[m][n] = sum_k A[m][k] * W[n][k] + bias[n] ----------------
template<int MODE>
__global__ __launch_bounds__(256) void gemm_bt(
        const ushort* __restrict__ A,   // M x K bf16 row-major
        const ushort* __restrict__ W,   // N x K bf16 row-major
        const float* __restrict__ bias, // N
        void* __restrict__ out, int M, int N, int K) {
    __shared__ ushort As[64 * 32];
    __shared__ ushort Bs[128 * 32];
    const int tid = threadIdx.x;
    const int w = tid >> 6, lane = tid & 63;
    const int lr = lane & 15, lg = lane >> 4;
    const int nTiles = N >> 7;
    const int nwg = gridDim.x;
    const int cpx = nwg >> 3;
    int lid = (blockIdx.x & 7) * cpx + (blockIdx.x >> 3);
    const int tM = (lid / nTiles) << 6;
    const int tN = (lid % nTiles) << 7;
    const int wr = (w >> 1) * 32, wc = (w & 1) * 64;

    f32x4 acc[2][4] = {};

    const int cA = w * 64 + lane;
    const int cB0 = w * 128 + lane;
    const int cB1 = w * 128 + 64 + lane;
    const ushort* gA  = A + (size_t)(tM + (cA  >> 2)) * K + (cA  & 3) * 8;
    const ushort* gB0 = W + (size_t)(tN + (cB0 >> 2)) * K + (cB0 & 3) * 8;
    const ushort* gB1 = W + (size_t)(tN + (cB1 >> 2)) * K + (cB1 & 3) * 8;
    ushort* lA  = As + w * 512;
    ushort* lB0 = Bs + w * 1024;
    ushort* lB1 = Bs + w * 1024 + 512;

    for (int k0 = 0; k0 < K; k0 += 32) {
        gld_lds16(gA  + k0, lA);
        gld_lds16(gB0 + k0, lB0);
        gld_lds16(gB1 + k0, lB1);
        __syncthreads();

        bf16x8 af[2], bfr[4];
#pragma unroll
        for (int i = 0; i < 2; i++)
            af[i] = *(const bf16x8*)(As + (wr + i * 16 + lr) * 32 + lg * 8);
#pragma unroll
        for (int i = 0; i < 4; i++)
            bfr[i] = *(const bf16x8*)(Bs + (wc + i * 16 + lr) * 32 + lg * 8);
#pragma unroll
        for (int mi = 0; mi < 2; mi++)
#pragma unroll
            for (int ni = 0; ni < 4; ni++)
                acc[mi][ni] = __builtin_amdgcn_mfma_f32_16x16x32_bf16(
                    af[mi], bfr[ni], acc[mi][ni], 0, 0, 0);
        __syncthreads();
    }

#pragma unroll
    for (int mi = 0; mi < 2; mi++) {
        const int row0 = tM + wr + mi * 16 + lg * 4;
#pragma unroll
        for (int ni = 0; ni < 4; ni++) {
            const int col = tN + wc + ni * 16 + lr;
            const float bv = bias[col];
#pragma unroll
            for (int r = 0; r < 4; r++) {
                float vv = acc[mi][ni][r] + bv;
                int m = row0 + r;
                if (MODE == 2) {
                    ((float*)out)[(size_t)m * N + col] = vv;
                } else {
                    int b = m >> 11, s = m & (SEQ - 1);
                    int h = col >> 6, d = col & (DK - 1);
                    if (MODE == 0)
                        ((ushort*)out)[(((size_t)(b * NHEADS + h) * SEQ + s) * DK) + d] = f2bf_u(vv);
                    else
                        ((ushort*)out)[(((size_t)(b * NHEADS + h) * DK + d) * SEQ) + s] = f2bf_u(vv);
                }
            }
        }
    }
}

// ---------------- attention: swapped-QK 32x32, software-pipelined ----------------
#define SCALE2 0.18033688011120542f   // 0.125 * log2(e)

__device__ __forceinline__ bf16x8 pack_pa(const float* p) {
    uint a, b, c, d;
    asm("v_cvt_pk_bf16_f32 %0, %1, %2" : "=v"(a) : "v"(p[0]), "v"(p[1]));
    asm("v_cvt_pk_bf16_f32 %0, %1, %2" : "=v"(b) : "v"(p[4]), "v"(p[5]));
    asm("v_cvt_pk_bf16_f32 %0, %1, %2" : "=v"(c) : "v"(p[2]), "v"(p[3]));
    asm("v_cvt_pk_bf16_f32 %0, %1, %2" : "=v"(d) : "v"(p[6]), "v"(p[7]));
    asm("v_permlane32_swap_b32 %0, %1" : "+v"(a), "+v"(b));
    asm("v_permlane32_swap_b32 %0, %1" : "+v"(c), "+v"(d));
    union { u32x4 u; bf16x8 h; } cv;
    cv.u = (u32x4){a, c, b, d};
    return cv.h;
}

// cross-half (lane <-> lane^32) combine via the COMPILER-MANAGED permlane
// builtin. R4 bug: "+v"(t),"+v"(u) with t==u coalesced into one VGPR (swap, not
// combine). R5 bug: v_mov + permlane inside ONE asm block = unhandled
// VALU->cross-lane hazard (no wait-states inserted within inline asm).
// __builtin_amdgcn_permlane32_swap returns {vdst', vsrc'}; compiler handles
// register copies and hazards.  fmax/add of the two results = cross-half combine.
__device__ __forceinline__ float xmax32(float x) {
    u32x2 r = __builtin_amdgcn_permlane32_swap(__float_as_uint(x), __float_as_uint(x), false, false);
    return fmaxf(__uint_as_float(r[0]), __uint_as_float(r[1]));
}
__device__ __forceinline__ float xadd32(float x) {
    u32x2 r = __builtin_amdgcn_permlane32_swap(__float_as_uint(x), __float_as_uint(x), false, false);
    return __uint_as_float(r[0]) + __uint_as_float(r[1]);
}

__global__ __launch_bounds__(256) void attn_fwd32(
        const ushort* __restrict__ Qh, const ushort* __restrict__ Kh,
        const ushort* __restrict__ Vt, const float* __restrict__ mbias,
        ushort* __restrict__ ctx) {
    const int w = threadIdx.x >> 6;
    const int l = threadIdx.x & 63;
    const int q32 = l & 31, hi = l >> 5;

    int lid = (blockIdx.x & 7) * 64 + (blockIdx.x >> 3);
    const int qblk = lid & 15;
    const int bh = lid >> 4;
    const int b = bh >> 4, h = bh & 15;
    const int q0 = qblk * 128 + w * 32;

    const ushort* Qp  = Qh + (size_t)bh * SEQ * DK + (size_t)(q0 + q32) * DK + hi * 8;
    const ushort* Kp  = Kh + (size_t)bh * SEQ * DK + (size_t)q32 * DK + hi * 8;
    const ushort* Vp0 = Vt + (size_t)bh * DK * SEQ + (size_t)q32 * SEQ + hi * 8;
    const ushort* Vp1 = Vp0 + (size_t)32 * SEQ;
    const float* mrow = mbias + b * SEQ + hi * 4;

    bf16x8 qf[4];
#pragma unroll
    for (int dc = 0; dc < 4; dc++)
        qf[dc] = *(const bf16x8*)(Qp + dc * 16);

    f32x16 c0 = {}, c1 = {};
    float m2 = -1e30f, lrun = 0.f;

    bf16x8 kbuf[4];
    auto loadK = [&](int tt) {
        const ushort* kp = Kp + (size_t)((tt & (NT - 1)) * 32) * DK;
        kbuf[0] = *(const bf16x8*)(kp);
        kbuf[1] = *(const bf16x8*)(kp + 16);
        kbuf[2] = *(const bf16x8*)(kp + 32);
        kbuf[3] = *(const bf16x8*)(kp + 48);
    };
    auto qk = [&](f32x16& sd) {
        f32x16 z = {};
        __builtin_amdgcn_s_setprio(1);
#pragma unroll
        for (int dc = 0; dc < 4; dc++)
            z = __builtin_amdgcn_mfma_f32_32x32x16_bf16(kbuf[dc], qf[dc], z, 0, 0, 0);
        __builtin_amdgcn_s_setprio(0);
        sd = z;
    };
    auto softpv = [&](f32x16& s, bf16x8 vc0, bf16x8 vc1, bf16x8 vc2, bf16x8 vc3, int t) {
        const int kv0 = t * 32;
        float4 mb[4];
#pragma unroll
        for (int g = 0; g < 4; g++)
            mb[g] = *reinterpret_cast<const float4*>(mrow + kv0 + g * 8);
        float p[16];
#pragma unroll
        for (int r = 0; r < 16; r++)
            p[r] = fmaf(s[r], SCALE2, reinterpret_cast<const float*>(&mb[r >> 2])[r & 3]);
        float m01 = fmaxf(p[0], p[1]),   m23 = fmaxf(p[2], p[3]);
        float m45 = fmaxf(p[4], p[5]),   m67 = fmaxf(p[6], p[7]);
        float m89 = fmaxf(p[8], p[9]),   mab = fmaxf(p[10], p[11]);
        float mcd = fmaxf(p[12], p[13]), mef = fmaxf(p[14], p[15]);
        float pm = fmaxf(fmaxf(fmaxf(m01, m23), fmaxf(m45, m67)),
                         fmaxf(fmaxf(m89, mab), fmaxf(mcd, mef)));
        pm = xmax32(pm);
        if (__any(pm - m2 > 8.0f)) {          // defer-max (T13)
            float mnew = fmaxf(m2, pm);
            float alpha = exp2f(m2 - mnew);
            m2 = mnew; lrun *= alpha;
#pragma unroll
            for (int r = 0; r < 16; r++) {
                float aT = __shfl(alpha, (r & 3) + 8 * (r >> 2) + 4 * hi);
                c0[r] *= aT; c1[r] *= aT;
            }
        }
        float rs = 0.f;
#pragma unroll
        for (int r = 0; r < 16; r++) { p[r] = exp2f(p[r] - m2); rs += p[r]; }
        lrun += xadd32(rs);
        bf16x8 pa0 = pack_pa(p);
        bf16x8 pa1 = pack_pa(p + 8);
        __builtin_amdgcn_s_setprio(1);
        c0 = __builtin_amdgcn_mfma_f32_32x32x16_bf16(pa0, vc0, c0, 0, 0, 0);
        c1 = __builtin_amdgcn_mfma_f32_32x32x16_bf16(pa0, vc2, c1, 0, 0, 0);
        c0 = __builtin_amdgcn_mfma_f32_32x32x16_bf16(pa1, vc1, c0, 0, 0, 0);
        c1 = __builtin_amdgcn_mfma_f32_32x32x16_bf16(pa1, vc3, c1, 0, 0, 0);
        __builtin_amdgcn_s_setprio(0);
    };

    // prologue: K(0) -> sA; prefetch K(1)
    f32x16 sA, sB;
    loadK(0);
    qk(sA);
    loadK(1);

    // steady state, 2x unrolled ping-pong on sA/sB:
    //   iter(t): V(t) loads; s_next = QK(K(t+1)); prefetch K(t+2); softpv(s_cur, t)
    for (int t = 0; t < NT; t += 2) {
        {
            const int kv0 = t * 32;
            bf16x8 vc0 = *(const bf16x8*)(Vp0 + kv0);
            bf16x8 vc1 = *(const bf16x8*)(Vp0 + kv0 + 16);
            bf16x8 vc2 = *(const bf16x8*)(Vp1 + kv0);
            bf16x8 vc3 = *(const bf16x8*)(Vp1 + kv0 + 16);
            qk(sB);                 // tile t+1
            loadK(t + 2);
            softpv(sA, vc0, vc1, vc2, vc3, t);
        }
        {
            const int kv0 = (t + 1) * 32;
            bf16x8 vc0 = *(const bf16x8*)(Vp0 + kv0);
            bf16x8 vc1 = *(const bf16x8*)(Vp0 + kv0 + 16);
            bf16x8 vc2 = *(const bf16x8*)(Vp1 + kv0);
            bf16x8 vc3 = *(const bf16x8*)(Vp1 + kv0 + 16);
            qk(sA);                 // tile t+2 (garbage on last iter, unused)
            loadK(t + 3);
            softpv(sB, vc0, vc1, vc2, vc3, t + 1);
        }
    }

    float rl = 1.0f / lrun;
#pragma unroll
    for (int r = 0; r < 16; r++) {
        int crow = (r & 3) + 8 * (r >> 2) + 4 * hi;
        float rlT = __shfl(rl, crow);
        int qq = q0 + crow;
        size_t base = (size_t)(b * SEQ + qq) * DMODEL + h * DK;
        ctx[base + q32]      = f2bf_u(c0[r] * rlT);
        ctx[base + 32 + q32] = f2bf_u(c1[r] * rlT);
    }
}

extern "C" void kernel_launch(void* const* d_in, const int* in_sizes, int n_in,
                              void* d_out, int out_size, void* d_ws, size_t ws_size,
                              hipStream_t stream) {
    const float* q    = (const float*)d_in[0];
    const float* k    = (const float*)d_in[1];
    const float* v    = (const float*)d_in[2];
    const int*   mask = (const int*)d_in[3];
    const float* Wq   = (const float*)d_in[4];
    const float* bq   = (const float*)d_in[5];
    const float* Wk   = (const float*)d_in[6];
    const float* bk   = (const float*)d_in[7];
    const float* Wv   = (const float*)d_in[8];
    const float* bv   = (const float*)d_in[9];
    const float* Wo   = (const float*)d_in[10];
    const float* bo   = (const float*)d_in[11];

    char* ws = (char*)d_ws;
    ushort* qb   = (ushort*)(ws + (size_t)0);
    ushort* kb   = (ushort*)(ws + ((size_t)8  << 20));
    ushort* vb   = (ushort*)(ws + ((size_t)16 << 20));
    ushort* Wqb  = (ushort*)(ws + ((size_t)24 << 20));
    ushort* Wkb  = (ushort*)(ws + ((size_t)26 << 20));
    ushort* Wvb  = (ushort*)(ws + ((size_t)28 << 20));
    ushort* Wob  = (ushort*)(ws + ((size_t)30 << 20));
    ushort* Qh   = (ushort*)(ws + ((size_t)32 << 20));
    ushort* Kh   = (ushort*)(ws + ((size_t)40 << 20));
    ushort* Vt   = (ushort*)(ws + ((size_t)48 << 20));
    ushort* ctxb = (ushort*)(ws + ((size_t)56 << 20));
    float*  mbias = (float*)(ws + (size_t)0);   // overlaps qb (dead after Q GEMM)

    cast_all<<<16384, 256, 0, stream>>>(q, k, v, Wq, Wk, Wv, Wo,
                                        qb, kb, vb, Wqb, Wkb, Wvb, Wob);

    const int M = BATCH * SEQ;
    const int gemmGrid = (M / 64) * (DMODEL / 128);   // 512
    gemm_bt<0><<<gemmGrid, 256, 0, stream>>>(qb, Wqb, bq, Qh, M, DMODEL, DMODEL);
    gemm_bt<0><<<gemmGrid, 256, 0, stream>>>(kb, Wkb, bk, Kh, M, DMODEL, DMODEL);
    gemm_bt<1><<<gemmGrid, 256, 0, stream>>>(vb, Wvb, bv, Vt, M, DMODEL, DMODEL);

    mask2bias<<<BATCH * SEQ / 1024, 256, 0, stream>>>(mask, mbias);

    attn_fwd32<<<BATCH * NHEADS * (SEQ / 128), 256, 0, stream>>>(Qh, Kh, Vt, mbias, ctxb);

    gemm_bt<2><<<gemmGrid, 256, 0, stream>>>(ctxb, Wob, bo, (void*)d_out, M, DMODEL, DMODEL);
}

// Round 7
// 161.706 us; speedup vs baseline: 1.4344x; 1.4344x over previous
//
#include <hip/hip_runtime.h>
#include <hip/hip_bf16.h>
#include <cstdint>
#include <cstddef>

#define DMODEL 1024
#define NHEADS 16
#define DK 64
#define SEQ 2048
#define BATCH 2
#define NT (SEQ / 32)

typedef short bf16x8 __attribute__((ext_vector_type(8)));
typedef float f32x4 __attribute__((ext_vector_type(4)));
typedef float f32x16 __attribute__((ext_vector_type(16)));
typedef unsigned int u32x2 __attribute__((ext_vector_type(2)));
typedef unsigned int u32x4 __attribute__((ext_vector_type(4)));

typedef const __attribute__((address_space(1))) void* gas_ptr;
typedef __attribute__((address_space(3))) void* las_ptr;

__device__ __forceinline__ void gld_lds16(const void* g, void* l) {
    __builtin_amdgcn_global_load_lds((gas_ptr)g, (las_ptr)l, 16, 0, 0);
}

__device__ __forceinline__ ushort f2bf_u(float f) {
    uint32_t x = __float_as_uint(f);
    x += 0x7fff + ((x >> 16) & 1);   // RNE
    return (ushort)(x >> 16);
}

// ---------------- fused cast fp32 -> bf16 (7 arrays, 1 launch) ----------------
__global__ __launch_bounds__(256) void cast_all(
        const float* __restrict__ q, const float* __restrict__ k,
        const float* __restrict__ v, const float* __restrict__ Wq,
        const float* __restrict__ Wk, const float* __restrict__ Wv,
        const float* __restrict__ Wo,
        ushort* __restrict__ qb, ushort* __restrict__ kb, ushort* __restrict__ vb,
        ushort* __restrict__ Wqb, ushort* __restrict__ Wkb,
        ushort* __restrict__ Wvb, ushort* __restrict__ Wob) {
    int bid = blockIdx.x;
    const float* src; ushort* dst; int base;
    if      (bid <  4096) { src = q;  dst = qb;  base = bid; }
    else if (bid <  8192) { src = k;  dst = kb;  base = bid - 4096; }
    else if (bid < 12288) { src = v;  dst = vb;  base = bid - 8192; }
    else if (bid < 13312) { src = Wq; dst = Wqb; base = bid - 12288; }
    else if (bid < 14336) { src = Wk; dst = Wkb; base = bid - 13312; }
    else if (bid < 15360) { src = Wv; dst = Wvb; base = bid - 14336; }
    else                  { src = Wo; dst = Wob; base = bid - 15360; }
    int i = base * 1024 + threadIdx.x * 4;
    float4 f = *reinterpret_cast<const float4*>(src + i);
    ushort4 o;
    o.x = f2bf_u(f.x); o.y = f2bf_u(f.y); o.z = f2bf_u(f.z); o.w = f2bf_u(f.w);
    *reinterpret_cast<ushort4*>(dst + i) = o;
}

// ---------------- mask -> additive bias (fp32) ----------------
__global__ __launch_bounds__(256) void mask2bias(
        const int* __restrict__ m, float* __restrict__ mb) {
    int i = (blockIdx.x * 256 + threadIdx.x) * 4;
    int4 mk = *reinterpret_cast<const int4*>(m + i);
    float4 o;
    o.x = mk.x ? 0.f : -1e9f;
    o.y = mk.y ? 0.f : -1e9f;
    o.z = mk.z ? 0.f : -1e9f;
    o.w = mk.w ? 0.f : -1e9f;
    *reinterpret_cast<float4*>(mb + i) = o;
}

// ---------------- GEMM: C[m][n] = sum_k A[m][k] * W[n][k] + bias[n] ----------------
template<int MODE>
__global__ __launch_bounds__(256) void gemm_bt(
        const ushort* __restrict__ A,   // M x K bf16 row-major
        const ushort* __restrict__ W,   // N x K bf16 row-major
        const float* __restrict__ bias, // N
        void* __restrict__ out, int M, int N, int K) {
    __shared__ ushort As[64 * 32];
    __shared__ ushort Bs[128 * 32];
    const int tid = threadIdx.x;
    const int w = tid >> 6, lane = tid & 63;
    const int lr = lane & 15, lg = lane >> 4;
    const int nTiles = N >> 7;
    const int nwg = gridDim.x;
    const int cpx = nwg >> 3;
    int lid = (blockIdx.x & 7) * cpx + (blockIdx.x >> 3);
    const int tM = (lid / nTiles) << 6;
    const int tN = (lid % nTiles) << 7;
    const int wr = (w >> 1) * 32, wc = (w & 1) * 64;

    f32x4 acc[2][4] = {};

    const int cA = w * 64 + lane;
    const int cB0 = w * 128 + lane;
    const int cB1 = w * 128 + 64 + lane;
    const ushort* gA  = A + (size_t)(tM + (cA  >> 2)) * K + (cA  & 3) * 8;
    const ushort* gB0 = W + (size_t)(tN + (cB0 >> 2)) * K + (cB0 & 3) * 8;
    const ushort* gB1 = W + (size_t)(tN + (cB1 >> 2)) * K + (cB1 & 3) * 8;
    ushort* lA  = As + w * 512;
    ushort* lB0 = Bs + w * 1024;
    ushort* lB1 = Bs + w * 1024 + 512;

    for (int k0 = 0; k0 < K; k0 += 32) {
        gld_lds16(gA  + k0, lA);
        gld_lds16(gB0 + k0, lB0);
        gld_lds16(gB1 + k0, lB1);
        __syncthreads();

        bf16x8 af[2], bfr[4];
#pragma unroll
        for (int i = 0; i < 2; i++)
            af[i] = *(const bf16x8*)(As + (wr + i * 16 + lr) * 32 + lg * 8);
#pragma unroll
        for (int i = 0; i < 4; i++)
            bfr[i] = *(const bf16x8*)(Bs + (wc + i * 16 + lr) * 32 + lg * 8);
#pragma unroll
        for (int mi = 0; mi < 2; mi++)
#pragma unroll
            for (int ni = 0; ni < 4; ni++)
                acc[mi][ni] = __builtin_amdgcn_mfma_f32_16x16x32_bf16(
                    af[mi], bfr[ni], acc[mi][ni], 0, 0, 0);
        __syncthreads();
    }

#pragma unroll
    for (int mi = 0; mi < 2; mi++) {
        const int row0 = tM + wr + mi * 16 + lg * 4;
#pragma unroll
        for (int ni = 0; ni < 4; ni++) {
            const int col = tN + wc + ni * 16 + lr;
            const float bv = bias[col];
#pragma unroll
            for (int r = 0; r < 4; r++) {
                float vv = acc[mi][ni][r] + bv;
                int m = row0 + r;
                if (MODE == 2) {
                    ((float*)out)[(size_t)m * N + col] = vv;
                } else {
                    int b = m >> 11, s = m & (SEQ - 1);
                    int h = col >> 6, d = col & (DK - 1);
                    if (MODE == 0)
                        ((ushort*)out)[(((size_t)(b * NHEADS + h) * SEQ + s) * DK) + d] = f2bf_u(vv);
                    else
                        ((ushort*)out)[(((size_t)(b * NHEADS + h) * DK + d) * SEQ) + s] = f2bf_u(vv);
                }
            }
        }
    }
}

// ---------------- attention: swapped-QK 32x32, LDS-staged K/V (2-phase) --------
// Block = 4 waves x 32 q-rows. Per kv-tile (32): K (32x64) and V (64x32, stored
// as paired rows [q32][d | d+32]) staged via ONE global_load_lds each (4KB,
// coalesced, source pre-swizzled so reads are ~conflict-free). Mask bias staged
// once (broadcast reads). Double-buffered: STAGE(t+1); compute(t); barrier.
#define SCALE2 0.18033688011120542f   // 0.125 * log2(e)

__device__ __forceinline__ bf16x8 pack_pa(const float* p) {
    uint a, b, c, d;
    asm("v_cvt_pk_bf16_f32 %0, %1, %2" : "=v"(a) : "v"(p[0]), "v"(p[1]));
    asm("v_cvt_pk_bf16_f32 %0, %1, %2" : "=v"(b) : "v"(p[4]), "v"(p[5]));
    asm("v_cvt_pk_bf16_f32 %0, %1, %2" : "=v"(c) : "v"(p[2]), "v"(p[3]));
    asm("v_cvt_pk_bf16_f32 %0, %1, %2" : "=v"(d) : "v"(p[6]), "v"(p[7]));
    asm("v_permlane32_swap_b32 %0, %1" : "+v"(a), "+v"(b));
    asm("v_permlane32_swap_b32 %0, %1" : "+v"(c), "+v"(d));
    union { u32x4 u; bf16x8 h; } cv;
    cv.u = (u32x4){a, c, b, d};
    return cv.h;
}

// cross-half (lane <-> lane^32) combine via compiler-managed permlane builtin.
__device__ __forceinline__ float xmax32(float x) {
    u32x2 r = __builtin_amdgcn_permlane32_swap(__float_as_uint(x), __float_as_uint(x), false, false);
    return fmaxf(__uint_as_float(r[0]), __uint_as_float(r[1]));
}
__device__ __forceinline__ float xadd32(float x) {
    u32x2 r = __builtin_amdgcn_permlane32_swap(__float_as_uint(x), __float_as_uint(x), false, false);
    return __uint_as_float(r[0]) + __uint_as_float(r[1]);
}

__global__ __launch_bounds__(256) void attn_fwd32(
        const ushort* __restrict__ Qh, const ushort* __restrict__ Kh,
        const ushort* __restrict__ Vt, const float* __restrict__ mbias,
        ushort* __restrict__ ctx) {
    __shared__ ushort Ks[2][2048];   // [kv=32][chunk=8x16B]  (4KB per buf)
    __shared__ ushort Vs[2][2048];   // [q32=32][d|d+32 paired, 8x16B chunks]
    __shared__ float  Ml[SEQ];       // mask bias row for this batch (8KB)

    const int tid = threadIdx.x;
    const int w = tid >> 6;
    const int l = tid & 63;
    const int q32 = l & 31, hi = l >> 5;
    const int q7 = q32 & 7;

    int lid = (blockIdx.x & 7) * 64 + (blockIdx.x >> 3);
    const int qblk = lid & 15;
    const int bh = lid >> 4;
    const int b = bh >> 4, h = bh & 15;
    const int q0 = qblk * 128 + w * 32;

    const ushort* Qp = Qh + (size_t)bh * SEQ * DK + (size_t)(q0 + q32) * DK + hi * 8;
    const ushort* Kg = Kh + (size_t)bh * SEQ * DK;
    const ushort* Vg = Vt + (size_t)bh * DK * SEQ;

    // staging constants: thread tid owns LDS chunk tid (16B). Source is
    // pre-swizzled (rule #21): LDS slot (row, cs) holds data chunk cs^(row&7).
    const int srow = tid >> 3;                 // 0..31
    const int scs  = (tid & 7) ^ (srow & 7);   // swizzled data chunk
    const ushort* Ksrc = Kg + (size_t)srow * DK + scs * 8;                      // +kv0*DK
    const ushort* Vsrc = Vg + (size_t)(srow + ((scs & 4) << 3)) * SEQ + (scs & 3) * 8;  // +kv0

    // stage mask bias row (2048 floats): 2 rounds of 16B/thread, wave-uniform dest
    {
        const float* mg = mbias + (size_t)b * SEQ;
        gld_lds16(mg + tid * 4,        &Ml[w * 256]);
        gld_lds16(mg + 1024 + tid * 4, &Ml[1024 + w * 256]);
    }

    auto STAGE = [&](int buf, int t) {
        const int kv0 = t * 32;
        gld_lds16(Ksrc + (size_t)kv0 * DK, &Ks[buf][w * 512]);
        gld_lds16(Vsrc + kv0,              &Vs[buf][w * 512]);
    };

    bf16x8 qf[4];
#pragma unroll
    for (int dc = 0; dc < 4; dc++)
        qf[dc] = *(const bf16x8*)(Qp + dc * 16);

    f32x16 c0 = {}, c1 = {};
    float m2 = -1e30f, lrun = 0.f;

    STAGE(0, 0);
    __syncthreads();   // drains stage vmcnt (compiler-inserted)

    for (int t = 0; t < NT; ++t) {
        const int buf = t & 1;
        if (t + 1 < NT) STAGE(buf ^ 1, t + 1);

        const ushort* Kb = &Ks[buf][0];
        const ushort* Vb = &Vs[buf][0];

        // ---- QK^T (swapped): A-frag K[kv0+q32][dc*16+hi*8] ----
        bf16x8 kf[4];
#pragma unroll
        for (int dc = 0; dc < 4; dc++)
            kf[dc] = *(const bf16x8*)(Kb + q32 * 64 + (((dc * 2 + hi) ^ q7) * 8));
        f32x16 s = {};
        __builtin_amdgcn_s_setprio(1);
#pragma unroll
        for (int dc = 0; dc < 4; dc++)
            s = __builtin_amdgcn_mfma_f32_32x32x16_bf16(kf[dc], qf[dc], s, 0, 0, 0);
        __builtin_amdgcn_s_setprio(0);

        // ---- mask (LDS broadcast) + scale ----
        const int kv0 = t * 32;
        float4 mb[4];
#pragma unroll
        for (int g = 0; g < 4; g++)
            mb[g] = *reinterpret_cast<const float4*>(&Ml[kv0 + g * 8 + hi * 4]);
        float p[16];
#pragma unroll
        for (int r = 0; r < 16; r++)
            p[r] = fmaf(s[r], SCALE2, reinterpret_cast<const float*>(&mb[r >> 2])[r & 3]);

        // ---- tile max + defer-max rescale (T13) ----
        float m01 = fmaxf(p[0], p[1]),   m23 = fmaxf(p[2], p[3]);
        float m45 = fmaxf(p[4], p[5]),   m67 = fmaxf(p[6], p[7]);
        float m89 = fmaxf(p[8], p[9]),   mab = fmaxf(p[10], p[11]);
        float mcd = fmaxf(p[12], p[13]), mef = fmaxf(p[14], p[15]);
        float pm = fmaxf(fmaxf(fmaxf(m01, m23), fmaxf(m45, m67)),
                         fmaxf(fmaxf(m89, mab), fmaxf(mcd, mef)));
        pm = xmax32(pm);
        if (__any(pm - m2 > 8.0f)) {
            float mnew = fmaxf(m2, pm);
            float alpha = __builtin_amdgcn_exp2f(m2 - mnew);
            m2 = mnew; lrun *= alpha;
#pragma unroll
            for (int r = 0; r < 16; r++) {
                float aT = __shfl(alpha, (r & 3) + 8 * (r >> 2) + 4 * hi);
                c0[r] *= aT; c1[r] *= aT;
            }
        }

        // ---- exp + row-sum ----
        float rs = 0.f;
#pragma unroll
        for (int r = 0; r < 16; r++) {
            p[r] = __builtin_amdgcn_exp2f(p[r] - m2);
            rs += p[r];
        }
        lrun += xadd32(rs);

        // ---- P -> bf16 A-frags (in-register, T12) ----
        bf16x8 pa0 = pack_pa(p);
        bf16x8 pa1 = pack_pa(p + 8);

        // ---- V frags from LDS: V[kv0+ks*16+hi*8 ..][dt*32+q32] ----
        bf16x8 vc[4];
#pragma unroll
        for (int dt = 0; dt < 2; dt++)
#pragma unroll
            for (int ks = 0; ks < 2; ks++)
                vc[dt * 2 + ks] = *(const bf16x8*)(Vb + q32 * 64 + (((dt * 4 + ks * 2 + hi) ^ q7) * 8));

        __builtin_amdgcn_s_setprio(1);
        c0 = __builtin_amdgcn_mfma_f32_32x32x16_bf16(pa0, vc[0], c0, 0, 0, 0);
        c1 = __builtin_amdgcn_mfma_f32_32x32x16_bf16(pa0, vc[2], c1, 0, 0, 0);
        c0 = __builtin_amdgcn_mfma_f32_32x32x16_bf16(pa1, vc[1], c0, 0, 0, 0);
        c1 = __builtin_amdgcn_mfma_f32_32x32x16_bf16(pa1, vc[3], c1, 0, 0, 0);
        __builtin_amdgcn_s_setprio(0);

        __syncthreads();
    }

    // ---- epilogue ----
    float rl = 1.0f / lrun;
#pragma unroll
    for (int r = 0; r < 16; r++) {
        int crow = (r & 3) + 8 * (r >> 2) + 4 * hi;
        float rlT = __shfl(rl, crow);
        int qq = q0 + crow;
        size_t base = (size_t)(b * SEQ + qq) * DMODEL + h * DK;
        ctx[base + q32]      = f2bf_u(c0[r] * rlT);
        ctx[base + 32 + q32] = f2bf_u(c1[r] * rlT);
    }
}

extern "C" void kernel_launch(void* const* d_in, const int* in_sizes, int n_in,
                              void* d_out, int out_size, void* d_ws, size_t ws_size,
                              hipStream_t stream) {
    const float* q    = (const float*)d_in[0];
    const float* k    = (const float*)d_in[1];
    const float* v    = (const float*)d_in[2];
    const int*   mask = (const int*)d_in[3];
    const float* Wq   = (const float*)d_in[4];
    const float* bq   = (const float*)d_in[5];
    const float* Wk   = (const float*)d_in[6];
    const float* bk   = (const float*)d_in[7];
    const float* Wv   = (const float*)d_in[8];
    const float* bv   = (const float*)d_in[9];
    const float* Wo   = (const float*)d_in[10];
    const float* bo   = (const float*)d_in[11];

    char* ws = (char*)d_ws;
    ushort* qb   = (ushort*)(ws + (size_t)0);
    ushort* kb   = (ushort*)(ws + ((size_t)8  << 20));
    ushort* vb   = (ushort*)(ws + ((size_t)16 << 20));
    ushort* Wqb  = (ushort*)(ws + ((size_t)24 << 20));
    ushort* Wkb  = (ushort*)(ws + ((size_t)26 << 20));
    ushort* Wvb  = (ushort*)(ws + ((size_t)28 << 20));
    ushort* Wob  = (ushort*)(ws + ((size_t)30 << 20));
    ushort* Qh   = (ushort*)(ws + ((size_t)32 << 20));
    ushort* Kh   = (ushort*)(ws + ((size_t)40 << 20));
    ushort* Vt   = (ushort*)(ws + ((size_t)48 << 20));
    ushort* ctxb = (ushort*)(ws + ((size_t)56 << 20));
    float*  mbias = (float*)(ws + (size_t)0);   // overlaps qb (dead after Q GEMM)

    cast_all<<<16384, 256, 0, stream>>>(q, k, v, Wq, Wk, Wv, Wo,
                                        qb, kb, vb, Wqb, Wkb, Wvb, Wob);

    const int M = BATCH * SEQ;
    const int gemmGrid = (M / 64) * (DMODEL / 128);   // 512
    gemm_bt<0><<<gemmGrid, 256, 0, stream>>>(qb, Wqb, bq, Qh, M, DMODEL, DMODEL);
    gemm_bt<0><<<gemmGrid, 256, 0, stream>>>(kb, Wkb, bk, Kh, M, DMODEL, DMODEL);
    gemm_bt<1><<<gemmGrid, 256, 0, stream>>>(vb, Wvb, bv, Vt, M, DMODEL, DMODEL);

    mask2bias<<<BATCH * SEQ / 1024, 256, 0, stream>>>(mask, mbias);

    attn_fwd32<<<BATCH * NHEADS * (SEQ / 128), 256, 0, stream>>>(Qh, Kh, Vt, mbias, ctxb);

    gemm_bt<2><<<gemmGrid, 256, 0, stream>>>(ctxb, Wob, bo, (void*)d_out, M, DMODEL, DMODEL);
}